// Round 18
// baseline (237.161 us; speedup 1.0000x reference)
//
#include <hip/hip_runtime.h>
#include <hip/hip_fp8.h>
#include <math.h>
#include <utility>

// N = 100000 nodes, SEQ = 16, layers: 3 ->16 ->32 ->64 ->128 ->256 ->12(log_softmax)
// R18: spiral3 = fp8 gather (64-B h2 rows, halved line count — R17-verified) with
//   DUAL fp8 MFMA: w3 stored as q=e4m3(w) and r=e4m3(16(w-q)) packed 16B/chunk;
//   acc = (A x q) + (A x r)/16. No per-element dequant VALU (R17's 44% VALUBusy).
//   A staging row-minor (chunk stride 256B) -> ~4-way instead of ~8-way conflicts.
// spiral1/2: R12-proven bf16 depth-1 pipeline (spiral2 epilogue emits fp8 h2).
// fc1+fc2+log_softmax fused with MFMA fc2 (R15-proven).

typedef __bf16 bf16x8 __attribute__((ext_vector_type(8)));
typedef float f32x16 __attribute__((ext_vector_type(16)));
typedef long long2v __attribute__((ext_vector_type(2)));

template <int V> using ic = std::integral_constant<int, V>;

template <typename F, int... Is>
__device__ __forceinline__ void static_for_impl(F&& f, std::integer_sequence<int, Is...>) {
    (f(ic<Is>{}), ...);
}
template <int N_, typename F>
__device__ __forceinline__ void static_for(F&& f) {
    static_for_impl(static_cast<F&&>(f), std::make_integer_sequence<int, N_>{});
}

template <int N_>
__device__ __forceinline__ void wait_vmcnt() {
    static_assert(N_ <= 63, "vmcnt range");
    __builtin_amdgcn_s_waitcnt((N_ & 0xF) | (0x7 << 4) | (0xF << 8) | ((N_ >> 4) << 14));
}

__device__ __forceinline__ void memfence_sched() { __builtin_amdgcn_sched_barrier(0x000F); }

__device__ __forceinline__ float elu_f(float v) { return v > 0.f ? v : expm1f(v); }

__device__ __forceinline__ unsigned char to_fp8(float v) {
    __hip_fp8_e4m3 q(v);
    return (unsigned char)q.__x;
}
__device__ __forceinline__ float fp8_to_f(unsigned char b) {
    __hip_fp8_e4m3 q;
    q.__x = b;
    return (float)q;
}

// ------------------------------------------------ weight prep
// bf16 frag-major: dst chunk ((k/64)*8 + (k%64)/8)*C + col, elem k%8  <- src[col*K+k]
template <int K, int C>
__device__ __forceinline__ void swz_one(const float* __restrict__ src, __bf16* __restrict__ dst, int j)
{
    int col = j / K;
    int k = j & (K - 1);
    int chunk = ((k >> 6) * 8 + ((k & 63) >> 3)) * C + col;
    dst[chunk * 8 + (k & 7)] = (__bf16)src[j];
}

__global__ __launch_bounds__(256) void cvt_swz_kernel(const float* __restrict__ w1,
                                                      const float* __restrict__ w2,
                                                      const float* __restrict__ w3,
                                                      const float* __restrict__ f1,
                                                      const float* __restrict__ f2,
                                                      __bf16* __restrict__ d1,
                                                      __bf16* __restrict__ d2,
                                                      __bf16* __restrict__ df1,
                                                      __bf16* __restrict__ df2p,
                                                      unsigned char* __restrict__ dw3)
{
    int i = blockIdx.x * 256 + threadIdx.x;
    if (i < 8192)        swz_one<256, 32>(w1, d1, i);
    else if (i < 40960)  swz_one<512, 64>(w2, d2, i - 8192);
    else if (i < 73728)  swz_one<128, 256>(f1, df1, i - 40960);
    else if (i < 81920) {
        // fc2 padded to 32 cols, frag-major (K=256, C=32); inverse map over DEST index
        int d = i - 73728;
        int e = d & 7;
        int chunkIdx = d >> 3;
        int col = chunkIdx & 31;
        int q = chunkIdx >> 5;
        int k = (q >> 3) * 64 + (q & 7) * 8 + e;
        df2p[d] = (col < 12) ? (__bf16)f2[col * 256 + k] : (__bf16)0.f;
    } else if (i < 212992) {
        // w3 dual-fp8: chunk (k/8)*128+col is 16 B: [0..7]=q bytes, [8..15]=r bytes
        int j = i - 81920;
        int col = j >> 10;
        int k = j & 1023;
        float w = w3[j];
        unsigned char q8 = to_fp8(w);
        float r = 16.f * (w - fp8_to_f(q8));
        unsigned char r8 = to_fp8(r);
        size_t base = ((size_t)((k >> 3) * 128 + col)) * 16 + (k & 7);
        dw3[base] = q8;
        dw3[base + 8] = r8;
    }
}

// ------------------------------------------------ idx transpose: idxT[s*N + n] = idx[n*16 + s]
__global__ __launch_bounds__(256) void idxT_kernel(const int* __restrict__ idx,
                                                   int* __restrict__ idxT, int N)
{
    int i = blockIdx.x * 256 + threadIdx.x;
    if (i >= N * 16) return;
    int n = i >> 4, s = i & 15;
    idxT[s * N + n] = idx[i];
}

// ---------------------------------------------------------------- fc0: [N,3] -> [N,16] bf16
__global__ __launch_bounds__(256) void fc0_kernel(const float* __restrict__ x,
                                                  const float* __restrict__ w,
                                                  const float* __restrict__ b,
                                                  __bf16* __restrict__ h0, int N)
{
    int n = blockIdx.x * 256 + threadIdx.x;
    if (n >= N) return;
    float x0 = x[n * 3 + 0], x1 = x[n * 3 + 1], x2 = x[n * 3 + 2];
    __bf16 ob[16];
#pragma unroll
    for (int j = 0; j < 16; ++j)
        ob[j] = (__bf16)elu_f(w[j * 3 + 0] * x0 + w[j * 3 + 1] * x1 + w[j * 3 + 2] * x2 + b[j]);
    int4* dst = (int4*)&h0[(size_t)n * 16];
    dst[0] = *(int4*)&ob[0];
    dst[1] = *(int4*)&ob[8];
}

// ------------------------------------------- depth-1 pipelined bf16 MFMA gather-GEMM (R12)
// OUTF8: epilogue emits fp8 e4m3 instead of bf16 (used by spiral2 -> h2).
template <int CIN, int S, int COUT_B, int COUT_TOT, int TILE_M, int RW, int CW,
          bool GATHER, bool OUTF8, int MINW, int NN>
__global__ __launch_bounds__(256, MINW) void mfma_layer(const __bf16* __restrict__ hin,
                                                        const int* __restrict__ idxT,
                                                        const __bf16* __restrict__ Wsw,
                                                        const float* __restrict__ bias,
                                                        void* __restrict__ hout)
{
    constexpr int K = CIN * S;
    constexpr int NSTEP = K / 64;
    static_assert(K % 64 == 0, "K%64");
    constexpr int WM = TILE_M / RW;
    constexpr int WN = COUT_B / CW;
    constexpr int MT = WM / 32;
    constexpr int NT = WN / 32;
    constexpr int IPS = GATHER ? (64 / CIN) : 1;
    constexpr int D = WM / 8;
    constexpr int Bn = NT * 4;
    constexpr int I = GATHER ? D : 0;
    constexpr int NBUFS = 2;
    static_assert(RW * CW == 4, "4 waves");
    static_assert(WM == 32 || WM == 64, "1-2 row subtiles per wave");

    constexpr int AB = 4 * NBUFS * WM * 128;
    constexpr int CB = OUTF8 ? TILE_M * (COUT_B + 16) : TILE_M * (COUT_B + 8) * 2;
    constexpr int SH = AB > CB ? AB : CB;
    __shared__ __align__(16) char smem[SH];

    const int tid = threadIdx.x;
    const int lane = tid & 63;
    const int w = tid >> 6;
    const int wr = w / CW;
    const int wc = w % CW;
    const int ml = lane & 31;
    const int kh = lane >> 5;
    const int m0 = blockIdx.x * TILE_M;
    const int col0 = blockIdx.y * COUT_B;
    const int rbase = m0 + wr * WM;

    char* const Aw = smem + w * (NBUFS * WM * 128);

    int ioff[GATHER ? D : 1];
    int koff[GATHER ? D : 1];
    int gmr[GATHER ? 1 : D];
    int coff[GATHER ? 1 : D];
#pragma unroll
    for (int i = 0; i < D; ++i) {
        int r = i * 8 + (lane >> 3);
        int c = (lane & 7) ^ (r & 7);
        int gm = rbase + r; if (gm >= NN) gm = NN - 1;
        if constexpr (GATHER) {
            ioff[i] = ((c * 8) / CIN) * NN + gm;
            koff[i] = (c * 8) & (CIN - 1);
        } else {
            gmr[i] = gm;
            coff[i] = c * 8;
        }
    }

    bf16x8 bfr[2][NT][4];
    int myIdx[GATHER ? 3 : 1][GATHER ? D : 1];

    const __bf16* wlane = Wsw + ((size_t)(col0 + wc * WN + ml) + (size_t)kh * COUT_TOT) * 8;

    auto loadB = [&](auto sc) {
        constexpr int s = decltype(sc)::value;
        if constexpr (s < NSTEP) {
#pragma unroll
            for (int ni = 0; ni < NT; ++ni)
#pragma unroll
                for (int ks = 0; ks < 4; ++ks)
                    bfr[s & 1][ni][ks] = *(const bf16x8*)(wlane
                        + (size_t)(s * 8 + ks * 2) * COUT_TOT * 8 + ni * 32 * 8);
        }
    };
    auto loadIdxS = [&](auto sc) {
        constexpr int s = decltype(sc)::value;
        if constexpr (GATHER && s < NSTEP) {
#pragma unroll
            for (int i = 0; i < D; ++i)
                myIdx[s % 3][i] = idxT[(s * IPS) * NN + ioff[i]];
        }
    };
    auto issueDMA = [&](auto sc) {
        constexpr int s = decltype(sc)::value;
        if constexpr (s < NSTEP) {
            char* base = Aw + (s % NBUFS) * (WM * 128);
#pragma unroll
            for (int i = 0; i < D; ++i) {
                const __bf16* src;
                if constexpr (GATHER)
                    src = hin + (size_t)myIdx[s % 3][i] * CIN + koff[i];
                else
                    src = hin + (size_t)gmr[i] * K + s * 64 + coff[i];
                __builtin_amdgcn_global_load_lds(
                    (const __attribute__((address_space(1))) void*)src,
                    (__attribute__((address_space(3))) void*)(base + i * 1024),
                    16, 0, 0);
            }
        }
    };

    f32x16 acc[MT][NT];
#pragma unroll
    for (int mi = 0; mi < MT; ++mi)
#pragma unroll
        for (int ni = 0; ni < NT; ++ni) { f32x16 z = {}; acc[mi][ni] = z; }

    loadIdxS(ic<0>{});
    loadIdxS(ic<1>{});
    memfence_sched();
    loadB(ic<0>{});
    memfence_sched();
    issueDMA(ic<0>{});
    memfence_sched();
    loadIdxS(ic<2>{});
    memfence_sched();

    static_for<NSTEP>([&](auto sc) {
        constexpr int s = decltype(sc)::value;
        loadB(ic<s + 1>{});
        memfence_sched();
        issueDMA(ic<s + 1>{});
        memfence_sched();
        loadIdxS(ic<s + 3>{});
        memfence_sched();
        constexpr int NW = I * (s + 2 < NSTEP) + (Bn + D) * (s + 1 < NSTEP)
                         + I * (s + 3 < NSTEP);
        wait_vmcnt<NW>();
        memfence_sched();

        const char* base = Aw + (s % NBUFS) * (WM * 128);
        bf16x8 afr[MT][4];
#pragma unroll
        for (int mi = 0; mi < MT; ++mi)
#pragma unroll
            for (int ks = 0; ks < 4; ++ks) {
                int cb = ks * 2 + kh;
                afr[mi][ks] = *(const bf16x8*)(base + ((mi * 32 + ml) * 8 + (cb ^ (ml & 7))) * 16);
            }
#pragma unroll
        for (int ks = 0; ks < 4; ++ks)
#pragma unroll
            for (int mi = 0; mi < MT; ++mi)
#pragma unroll
                for (int ni = 0; ni < NT; ++ni)
                    acc[mi][ni] = __builtin_amdgcn_mfma_f32_32x32x16_bf16(
                        afr[mi][ks], bfr[s & 1][ni][ks], acc[mi][ni], 0, 0, 0);
    });

    // ---- epilogue
    __syncthreads();
    if constexpr (OUTF8) {
        unsigned char* Cs8 = (unsigned char*)smem;
        constexpr int LDC8 = COUT_B + 16;
#pragma unroll
        for (int ni = 0; ni < NT; ++ni) {
            const int col = wc * WN + ni * 32 + ml;
            const float bv = bias[col0 + col];
#pragma unroll
            for (int mi = 0; mi < MT; ++mi) {
#pragma unroll
                for (int r = 0; r < 16; ++r) {
                    int row = wr * WM + mi * 32 + ((r & 3) + 8 * (r >> 2) + 4 * kh);
                    Cs8[row * LDC8 + col] = to_fp8(elu_f(acc[mi][ni][r] + bv));
                }
            }
        }
        __syncthreads();
        constexpr int C16 = COUT_B / 16;
#pragma unroll
        for (int j2 = tid; j2 < TILE_M * C16; j2 += 256) {
            int row = j2 / C16, c16 = j2 % C16;
            int gm = m0 + row;
            if (gm < NN)
                *(int4*)((unsigned char*)hout + (size_t)gm * COUT_TOT + col0 + c16 * 16)
                    = *(int4*)&Cs8[row * LDC8 + c16 * 16];
        }
    } else {
        __bf16* Cs = (__bf16*)smem;
        constexpr int LDC = COUT_B + 8;
#pragma unroll
        for (int ni = 0; ni < NT; ++ni) {
            const int col = wc * WN + ni * 32 + ml;
            const float bv = bias[col0 + col];
#pragma unroll
            for (int mi = 0; mi < MT; ++mi) {
#pragma unroll
                for (int r = 0; r < 16; ++r) {
                    int row = wr * WM + mi * 32 + ((r & 3) + 8 * (r >> 2) + 4 * kh);
                    Cs[row * LDC + col] = (__bf16)elu_f(acc[mi][ni][r] + bv);
                }
            }
        }
        __syncthreads();
        constexpr int C8 = COUT_B / 8;
#pragma unroll
        for (int j2 = tid; j2 < TILE_M * C8; j2 += 256) {
            int row = j2 / C8, c8 = j2 % C8;
            int gm = m0 + row;
            if (gm < NN)
                *(int4*)&((__bf16*)hout)[(size_t)gm * COUT_TOT + col0 + c8 * 8] = *(int4*)&Cs[row * LDC + c8 * 8];
        }
    }
}

// ------------------------------------------- spiral3 DUAL-FP8: fp8 h2 gather + q/r fp8 MFMA
// TILE 64 (RW=2, CW=2), wave 32x64, K=1024, NSTEP=16.
// A staged row-minor: inst i, lane t -> row i*16+(t&15), chunk t>>4 (chunk stride 256 B).
__global__ __launch_bounds__(256, 2) void mfma3_dual(const unsigned char* __restrict__ h2f8, // [N,64] e4m3
                                                     const int* __restrict__ idxT,
                                                     const unsigned char* __restrict__ W3d,  // dual-fp8 (K=1024,C=128)
                                                     const float* __restrict__ bias,
                                                     __bf16* __restrict__ h3)
{
    constexpr int NN = 100000;
    constexpr int NSTEP = 16;
    constexpr int D = 2;        // DMA insts per step per wave
    constexpr int Bn = 8;       // B loads per step (NT=2 x 4 ks, b128 q||r)
    constexpr int I = 2;        // idx loads per step
    __shared__ __align__(16) char smem[17408];   // A: 4x2x2KB=16KB; epilogue 64x136 bf16

    const int tid = threadIdx.x;
    const int lane = tid & 63;
    const int w = tid >> 6;
    const int wr = w >> 1;
    const int wc = w & 1;
    const int ml = lane & 31;
    const int kh = lane >> 5;
    const int m0 = blockIdx.x * 64;
    const int rbase = m0 + wr * 32;

    char* const Aw = smem + w * 4096;

    // row-minor DMA geometry: inst i, lane t -> row i*16+(t&15), chunk t>>4
    int ioff[D], koff;
#pragma unroll
    for (int i = 0; i < D; ++i) {
        int gm = rbase + i * 16 + (lane & 15);
        if (gm >= NN) gm = NN - 1;
        ioff[i] = gm;
    }
    koff = (lane >> 4) * 16;

    long2v bqr[2][2][4];    // [buf][ni][ks]: x = q frag, y = r frag
    int myIdx[3][D];

    const unsigned char* wlane = W3d + ((size_t)(wc * 64 + ml) + (size_t)kh * 128) * 16;

    auto loadB = [&](auto sc) {
        constexpr int s = decltype(sc)::value;
        if constexpr (s < NSTEP) {
#pragma unroll
            for (int ni = 0; ni < 2; ++ni)
#pragma unroll
                for (int ks = 0; ks < 4; ++ks)
                    bqr[s & 1][ni][ks] = *(const long2v*)(wlane
                        + (size_t)(s * 8 + ks * 2) * 2048 + ni * 512);
        }
    };
    auto loadIdxS = [&](auto sc) {
        constexpr int s = decltype(sc)::value;
        if constexpr (s < NSTEP) {
#pragma unroll
            for (int i = 0; i < D; ++i)
                myIdx[s % 3][i] = idxT[(size_t)s * NN + ioff[i]];
        }
    };
    auto issueDMA = [&](auto sc) {
        constexpr int s = decltype(sc)::value;
        if constexpr (s < NSTEP) {
            char* base = Aw + (s & 1) * 2048;
#pragma unroll
            for (int i = 0; i < D; ++i) {
                const unsigned char* src = h2f8 + (size_t)myIdx[s % 3][i] * 64 + koff;
                __builtin_amdgcn_global_load_lds(
                    (const __attribute__((address_space(1))) void*)src,
                    (__attribute__((address_space(3))) void*)(base + i * 1024),
                    16, 0, 0);
            }
        }
    };

    f32x16 accq[2], accr[2];
    { f32x16 z = {}; accq[0] = z; accq[1] = z; accr[0] = z; accr[1] = z; }

    loadIdxS(ic<0>{});
    loadIdxS(ic<1>{});
    memfence_sched();
    loadB(ic<0>{});
    memfence_sched();
    issueDMA(ic<0>{});
    memfence_sched();
    loadIdxS(ic<2>{});
    memfence_sched();

    static_for<NSTEP>([&](auto sc) {
        constexpr int s = decltype(sc)::value;
        loadB(ic<s + 1>{});
        memfence_sched();
        issueDMA(ic<s + 1>{});
        memfence_sched();
        loadIdxS(ic<s + 3>{});
        memfence_sched();
        constexpr int NW = I * (s + 2 < NSTEP) + (Bn + D) * (s + 1 < NSTEP)
                         + I * (s + 3 < NSTEP);
        wait_vmcnt<NW>();
        memfence_sched();

        // A reads, row-minor: addr = (ml>>4)*1024 + ks*256 + (ml&15)*16 + kh*8
        const char* base = Aw + (s & 1) * 2048 + (ml >> 4) * 1024 + (ml & 15) * 16 + kh * 8;
        long afr[4];
#pragma unroll
        for (int ks = 0; ks < 4; ++ks)
            afr[ks] = *(const long*)(base + ks * 256);
#pragma unroll
        for (int ks = 0; ks < 4; ++ks)
#pragma unroll
            for (int ni = 0; ni < 2; ++ni) {
                accq[ni] = __builtin_amdgcn_mfma_f32_32x32x16_fp8_fp8(
                    afr[ks], bqr[s & 1][ni][ks].x, accq[ni], 0, 0, 0);
                accr[ni] = __builtin_amdgcn_mfma_f32_32x32x16_fp8_fp8(
                    afr[ks], bqr[s & 1][ni][ks].y, accr[ni], 0, 0, 0);
            }
    });

    // ---- epilogue: combine q + r/16, bias + ELU, bf16 h3, coalesced
    __syncthreads();
    __bf16* Cs = (__bf16*)smem;
#pragma unroll
    for (int ni = 0; ni < 2; ++ni) {
        const int col = wc * 64 + ni * 32 + ml;
        const float bv = bias[col];
#pragma unroll
        for (int r = 0; r < 16; ++r) {
            int row = wr * 32 + ((r & 3) + 8 * (r >> 2) + 4 * kh);
            float v = accq[ni][r] + 0.0625f * accr[ni][r] + bv;
            Cs[row * 136 + col] = (__bf16)elu_f(v);
        }
    }
    __syncthreads();
#pragma unroll
    for (int j2 = tid; j2 < 64 * 16; j2 += 256) {
        int row = j2 >> 4, c8 = j2 & 15;
        int gm = m0 + row;
        if (gm < NN)
            *(int4*)&h3[(size_t)gm * 128 + c8 * 8] = *(int4*)&Cs[row * 136 + c8 * 8];
    }
}

// ------------------------------------------- FUSED fc1 + fc2(MFMA) + log_softmax (R15)
__global__ __launch_bounds__(256, 3) void fc12_kernel(const __bf16* __restrict__ h3,   // [N,128]
                                                      const __bf16* __restrict__ Wsw,  // fc1 frag-major (K=128,C=256)
                                                      const float* __restrict__ bias1,
                                                      const __bf16* __restrict__ W2p,  // fc2 frag-major padded (K=256,C=32)
                                                      const float* __restrict__ bias2,
                                                      float* __restrict__ out)
{
    __shared__ __align__(16) char smem[32 * 264 * 2];
    const int tid = threadIdx.x;
    const int lane = tid & 63;
    const int w = tid >> 6;
    const int ml = lane & 31;
    const int kh = lane >> 5;
    const int m0 = blockIdx.x * 32;

    const __bf16* wlane = Wsw + ((size_t)(w * 64 + ml) + (size_t)kh * 256) * 8;
    bf16x8 bfr[2][2][4];
#pragma unroll
    for (int s = 0; s < 2; ++s)
#pragma unroll
        for (int ni = 0; ni < 2; ++ni)
#pragma unroll
            for (int ks = 0; ks < 4; ++ks)
                bfr[s][ni][ks] = *(const bf16x8*)(wlane
                    + (size_t)(s * 8 + ks * 2) * 256 * 8 + ni * 32 * 8);

    bf16x8 b2f[4];
#pragma unroll
    for (int ks = 0; ks < 4; ++ks)
        b2f[ks] = *(const bf16x8*)&W2p[((w * 8 + ks * 2 + kh) * 32 + ml) * 8];

#pragma unroll
    for (int t = 0; t < 2; ++t) {
        int j = w * 2 + t;
        int lr = j * 4 + (lane >> 4);
        int sc = (lane & 15) ^ (lr & 15);
        const __bf16* src = h3 + (size_t)(m0 + lr) * 128 + sc * 8;
        __builtin_amdgcn_global_load_lds(
            (const __attribute__((address_space(1))) void*)src,
            (__attribute__((address_space(3))) void*)(smem + j * 1024),
            16, 0, 0);
    }
    wait_vmcnt<0>();
    __syncthreads();

    f32x16 acc[2];
    { f32x16 z = {}; acc[0] = z; acc[1] = z; }
    const char* Ab = smem;
#pragma unroll
    for (int s = 0; s < 2; ++s) {
        bf16x8 afr[4];
#pragma unroll
        for (int ks = 0; ks < 4; ++ks) {
            int c16 = s * 8 + ks * 2 + kh;
            afr[ks] = *(const bf16x8*)(Ab + ml * 256 + ((c16 ^ (ml & 15)) * 16));
        }
#pragma unroll
        for (int ks = 0; ks < 4; ++ks)
#pragma unroll
            for (int ni = 0; ni < 2; ++ni)
                acc[ni] = __builtin_amdgcn_mfma_f32_32x32x16_bf16(afr[ks], bfr[s][ni][ks], acc[ni], 0, 0, 0);
    }
    __syncthreads();

    __bf16* Cs = (__bf16*)smem;
#pragma unroll
    for (int ni = 0; ni < 2; ++ni) {
        int col = w * 64 + ni * 32 + ml;
        float bv = bias1[col];
#pragma unroll
        for (int r = 0; r < 16; ++r) {
            int row = (r & 3) + 8 * (r >> 2) + 4 * kh;
            Cs[row * 264 + col] = (__bf16)elu_f(acc[ni][r] + bv);
        }
    }
    __syncthreads();

    bf16x8 a2[4];
#pragma unroll
    for (int ks = 0; ks < 4; ++ks)
        a2[ks] = *(const bf16x8*)&Cs[ml * 264 + w * 64 + ks * 16 + kh * 8];
    f32x16 acc2;
    { f32x16 z = {}; acc2 = z; }
#pragma unroll
    for (int ks = 0; ks < 4; ++ks)
        acc2 = __builtin_amdgcn_mfma_f32_32x32x16_bf16(a2[ks], b2f[ks], acc2, 0, 0, 0);
    __syncthreads();

    float* P = (float*)(smem + w * 4096);
#pragma unroll
    for (int r = 0; r < 16; ++r)
        P[((r & 3) + 8 * (r >> 2) + 4 * kh) * 32 + ml] = acc2[r];
    __syncthreads();

    float4 s4 = make_float4(0.f, 0.f, 0.f, 0.f);
#pragma unroll
    for (int pw = 0; pw < 4; ++pw) {
        float4 v = *(float4*)(smem + pw * 4096 + tid * 16);
        s4.x += v.x; s4.y += v.y; s4.z += v.z; s4.w += v.w;
    }
    __syncthreads();
    *(float4*)(smem + tid * 16) = s4;
    __syncthreads();

    if (tid < 32) {
        const float* L = (float*)smem + tid * 32;
        float logits[12], mx = -1e30f;
#pragma unroll
        for (int o = 0; o < 12; ++o) {
            logits[o] = L[o] + bias2[o];
            mx = fmaxf(mx, logits[o]);
        }
        float s = 0.f;
#pragma unroll
        for (int o = 0; o < 12; ++o) s += expf(logits[o] - mx);
        float lse = mx + logf(s);
        int n = m0 + tid;
        float4 o0 = make_float4(logits[0] - lse, logits[1] - lse, logits[2] - lse, logits[3] - lse);
        float4 o1 = make_float4(logits[4] - lse, logits[5] - lse, logits[6] - lse, logits[7] - lse);
        float4 o2 = make_float4(logits[8] - lse, logits[9] - lse, logits[10] - lse, logits[11] - lse);
        *(float4*)&out[(size_t)n * 12 + 0] = o0;
        *(float4*)&out[(size_t)n * 12 + 4] = o1;
        *(float4*)&out[(size_t)n * 12 + 8] = o2;
    }
}

extern "C" void kernel_launch(void* const* d_in, const int* in_sizes, int n_in,
                              void* d_out, int out_size, void* d_ws, size_t ws_size,
                              hipStream_t stream)
{
    const int N = 100000;
    const float* x     = (const float*)d_in[0];
    const int*   idx   = (const int*)  d_in[1];
    const float* fc0_w = (const float*)d_in[2];
    const float* fc0_b = (const float*)d_in[3];
    const float* w1    = (const float*)d_in[4];
    const float* b1    = (const float*)d_in[5];
    const float* w2    = (const float*)d_in[6];
    const float* b2    = (const float*)d_in[7];
    const float* w3    = (const float*)d_in[8];
    const float* b3    = (const float*)d_in[9];
    const float* fc1_w = (const float*)d_in[10];
    const float* fc1_b = (const float*)d_in[11];
    const float* fc2_w = (const float*)d_in[12];
    const float* fc2_b = (const float*)d_in[13];
    float* out = (float*)d_out;

    // ---- workspace layout
    char* ws = (char*)d_ws;
    const int n_w1 = 32 * 256, n_w2 = 64 * 512, n_fc1 = 256 * 128, n_fc2p = 32 * 256;
    __bf16* w1b = (__bf16*)ws;
    __bf16* w2b = w1b + n_w1;
    __bf16* f1b = w2b + n_w2;
    __bf16* f2b = f1b + n_fc1;
    unsigned char* w3d = (unsigned char*)(f2b + n_fc2p);   // 262144 bytes (dual fp8)
    size_t off = (((size_t)(n_w1 + n_w2 + n_fc1 + n_fc2p) * 2 + 262144) + 4095) & ~(size_t)4095;
    int* idxT = (int*)(ws + off);              off += (size_t)N * 16 * 4;
    __bf16* h0 = (__bf16*)(ws + off);          off += (size_t)N * 16 * 2;
    __bf16* h1 = (__bf16*)(ws + off);          off += (size_t)N * 32 * 2;
    unsigned char* h2f8 = (unsigned char*)(ws + off);  off += (size_t)N * 64;
    __bf16* h3 = (__bf16*)(ws + off);          off += (size_t)N * 128 * 2;

    cvt_swz_kernel<<<(212992 + 255) / 256, 256, 0, stream>>>(w1, w2, w3, fc1_w, fc2_w,
                                                             w1b, w2b, f1b, f2b, w3d);
    idxT_kernel<<<(N * 16 + 255) / 256, 256, 0, stream>>>(idx, idxT, N);
    fc0_kernel<<<(N + 255) / 256, 256, 0, stream>>>(x, fc0_w, fc0_b, h0, N);

    // spiral1: 16ch x16 -> 32 bf16. TILE 128 (RW=4, CW=1), NSTEP=4.
    mfma_layer<16, 16, 32, 32, 128, 4, 1, true, false, 3, 100000>
        <<<dim3((N + 127) / 128, 1), 256, 0, stream>>>(h0, idxT, w1b, b1, (void*)h1);
    // spiral2: 32ch x16 -> 64, OUTPUT fp8 h2. TILE 128 (RW=4, CW=1), NSTEP=8.
    mfma_layer<32, 16, 64, 64, 128, 4, 1, true, true, 3, 100000>
        <<<dim3((N + 127) / 128, 1), 256, 0, stream>>>(h1, idxT, w2b, b2, (void*)h2f8);
    // spiral3 DUAL-FP8: fp8 gather + q/r fp8 MFMA (no dequant VALU). [NEW]
    mfma3_dual<<<(N + 63) / 64, 256, 0, stream>>>(h2f8, idxT, w3d, b3, h3);
    // FUSED fc1 + fc2(MFMA) + log_softmax.
    fc12_kernel<<<N / 32, 256, 0, stream>>>(h3, f1b, fc1_b, f2b, fc2_b, out);
}

// Round 19
// 228.870 us; speedup vs baseline: 1.0362x; 1.0362x over previous
//
#include <hip/hip_runtime.h>
#include <hip/hip_fp8.h>
#include <math.h>
#include <utility>

// N = 100000 nodes, SEQ = 16, layers: 3 ->16 ->32 ->64 ->128 ->256 ->12(log_softmax)
// R19 = R17 (best: 224.9us) + two fixes for spiral3's mixed fp8-gather kernel:
//   1) row-minor A staging (R18-verified): ~4-way instead of ~8-way LDS conflicts.
//   2) dequant via __builtin_amdgcn_cvt_pk_f32_fp8 (HW packed cvt) — R17's
//      __hip_fp8 path is software on gfx950 (44% VALUBusy).
// spiral1/2: R12-proven bf16 depth-1 pipeline (spiral2 epilogue emits fp8 h2).
// fc1+fc2+log_softmax fused with MFMA fc2 (R15-proven).

typedef __bf16 bf16x8 __attribute__((ext_vector_type(8)));
typedef float f32x16 __attribute__((ext_vector_type(16)));
typedef float f32x2 __attribute__((ext_vector_type(2)));

template <int V> using ic = std::integral_constant<int, V>;

template <typename F, int... Is>
__device__ __forceinline__ void static_for_impl(F&& f, std::integer_sequence<int, Is...>) {
    (f(ic<Is>{}), ...);
}
template <int N_, typename F>
__device__ __forceinline__ void static_for(F&& f) {
    static_for_impl(static_cast<F&&>(f), std::make_integer_sequence<int, N_>{});
}

template <int N_>
__device__ __forceinline__ void wait_vmcnt() {
    static_assert(N_ <= 63, "vmcnt range");
    __builtin_amdgcn_s_waitcnt((N_ & 0xF) | (0x7 << 4) | (0xF << 8) | ((N_ >> 4) << 14));
}

__device__ __forceinline__ void memfence_sched() { __builtin_amdgcn_sched_barrier(0x000F); }

__device__ __forceinline__ float elu_f(float v) { return v > 0.f ? v : expm1f(v); }

__device__ __forceinline__ unsigned char to_fp8(float v) {
    __hip_fp8_e4m3 q(v);
    return (unsigned char)q.__x;
}

// 8 packed fp8 e4m3 -> bf16x8 via hardware packed converts
__device__ __forceinline__ bf16x8 dq8_fast(long v) {
    int lo = (int)v;
    int hi = (int)(v >> 32);
    f32x2 a = __builtin_amdgcn_cvt_pk_f32_fp8(lo, false);
    f32x2 b = __builtin_amdgcn_cvt_pk_f32_fp8(lo, true);
    f32x2 c = __builtin_amdgcn_cvt_pk_f32_fp8(hi, false);
    f32x2 d = __builtin_amdgcn_cvt_pk_f32_fp8(hi, true);
    bf16x8 r;
    r[0] = (__bf16)a[0]; r[1] = (__bf16)a[1];
    r[2] = (__bf16)b[0]; r[3] = (__bf16)b[1];
    r[4] = (__bf16)c[0]; r[5] = (__bf16)c[1];
    r[6] = (__bf16)d[0]; r[7] = (__bf16)d[1];
    return r;
}

// ------------------------------------------------ weight prep (all bf16 frag-major)
// dst chunk ((k/64)*8 + (k%64)/8)*C + col, elem k%8  <- src[col*K+k]
template <int K, int C>
__device__ __forceinline__ void swz_one(const float* __restrict__ src, __bf16* __restrict__ dst, int j)
{
    int col = j / K;
    int k = j & (K - 1);
    int chunk = ((k >> 6) * 8 + ((k & 63) >> 3)) * C + col;
    dst[chunk * 8 + (k & 7)] = (__bf16)src[j];
}

__global__ __launch_bounds__(256) void cvt_swz_kernel(const float* __restrict__ w1,
                                                      const float* __restrict__ w2,
                                                      const float* __restrict__ w3,
                                                      const float* __restrict__ f1,
                                                      const float* __restrict__ f2,
                                                      __bf16* __restrict__ d1,
                                                      __bf16* __restrict__ d2,
                                                      __bf16* __restrict__ d3,
                                                      __bf16* __restrict__ df1,
                                                      __bf16* __restrict__ df2p)
{
    int i = blockIdx.x * 256 + threadIdx.x;
    if (i < 8192)        swz_one<256, 32>(w1, d1, i);
    else if (i < 40960)  swz_one<512, 64>(w2, d2, i - 8192);
    else if (i < 172032) swz_one<1024, 128>(w3, d3, i - 40960);
    else if (i < 204800) swz_one<128, 256>(f1, df1, i - 172032);
    else if (i < 212992) {
        // fc2 padded to 32 cols, frag-major (K=256, C=32); inverse map over DEST index
        int d = i - 204800;
        int e = d & 7;
        int chunkIdx = d >> 3;
        int col = chunkIdx & 31;
        int q = chunkIdx >> 5;
        int k = (q >> 3) * 64 + (q & 7) * 8 + e;
        df2p[d] = (col < 12) ? (__bf16)f2[col * 256 + k] : (__bf16)0.f;
    }
}

// ------------------------------------------------ idx transpose: idxT[s*N + n] = idx[n*16 + s]
__global__ __launch_bounds__(256) void idxT_kernel(const int* __restrict__ idx,
                                                   int* __restrict__ idxT, int N)
{
    int i = blockIdx.x * 256 + threadIdx.x;
    if (i >= N * 16) return;
    int n = i >> 4, s = i & 15;
    idxT[s * N + n] = idx[i];
}

// ---------------------------------------------------------------- fc0: [N,3] -> [N,16] bf16
__global__ __launch_bounds__(256) void fc0_kernel(const float* __restrict__ x,
                                                  const float* __restrict__ w,
                                                  const float* __restrict__ b,
                                                  __bf16* __restrict__ h0, int N)
{
    int n = blockIdx.x * 256 + threadIdx.x;
    if (n >= N) return;
    float x0 = x[n * 3 + 0], x1 = x[n * 3 + 1], x2 = x[n * 3 + 2];
    __bf16 ob[16];
#pragma unroll
    for (int j = 0; j < 16; ++j)
        ob[j] = (__bf16)elu_f(w[j * 3 + 0] * x0 + w[j * 3 + 1] * x1 + w[j * 3 + 2] * x2 + b[j]);
    int4* dst = (int4*)&h0[(size_t)n * 16];
    dst[0] = *(int4*)&ob[0];
    dst[1] = *(int4*)&ob[8];
}

// ------------------------------------------- depth-1 pipelined bf16 MFMA gather-GEMM (R12)
// OUTF8: epilogue emits fp8 e4m3 instead of bf16 (used by spiral2 -> h2).
template <int CIN, int S, int COUT_B, int COUT_TOT, int TILE_M, int RW, int CW,
          bool GATHER, bool OUTF8, int MINW, int NN>
__global__ __launch_bounds__(256, MINW) void mfma_layer(const __bf16* __restrict__ hin,
                                                        const int* __restrict__ idxT,
                                                        const __bf16* __restrict__ Wsw,
                                                        const float* __restrict__ bias,
                                                        void* __restrict__ hout)
{
    constexpr int K = CIN * S;
    constexpr int NSTEP = K / 64;
    static_assert(K % 64 == 0, "K%64");
    constexpr int WM = TILE_M / RW;
    constexpr int WN = COUT_B / CW;
    constexpr int MT = WM / 32;
    constexpr int NT = WN / 32;
    constexpr int IPS = GATHER ? (64 / CIN) : 1;
    constexpr int D = WM / 8;
    constexpr int Bn = NT * 4;
    constexpr int I = GATHER ? D : 0;
    constexpr int NBUFS = 2;
    static_assert(RW * CW == 4, "4 waves");
    static_assert(WM == 32 || WM == 64, "1-2 row subtiles per wave");

    constexpr int AB = 4 * NBUFS * WM * 128;
    constexpr int CB = OUTF8 ? TILE_M * (COUT_B + 16) : TILE_M * (COUT_B + 8) * 2;
    constexpr int SH = AB > CB ? AB : CB;
    __shared__ __align__(16) char smem[SH];

    const int tid = threadIdx.x;
    const int lane = tid & 63;
    const int w = tid >> 6;
    const int wr = w / CW;
    const int wc = w % CW;
    const int ml = lane & 31;
    const int kh = lane >> 5;
    const int m0 = blockIdx.x * TILE_M;
    const int col0 = blockIdx.y * COUT_B;
    const int rbase = m0 + wr * WM;

    char* const Aw = smem + w * (NBUFS * WM * 128);

    int ioff[GATHER ? D : 1];
    int koff[GATHER ? D : 1];
    int gmr[GATHER ? 1 : D];
    int coff[GATHER ? 1 : D];
#pragma unroll
    for (int i = 0; i < D; ++i) {
        int r = i * 8 + (lane >> 3);
        int c = (lane & 7) ^ (r & 7);
        int gm = rbase + r; if (gm >= NN) gm = NN - 1;
        if constexpr (GATHER) {
            ioff[i] = ((c * 8) / CIN) * NN + gm;
            koff[i] = (c * 8) & (CIN - 1);
        } else {
            gmr[i] = gm;
            coff[i] = c * 8;
        }
    }

    bf16x8 bfr[2][NT][4];
    int myIdx[GATHER ? 3 : 1][GATHER ? D : 1];

    const __bf16* wlane = Wsw + ((size_t)(col0 + wc * WN + ml) + (size_t)kh * COUT_TOT) * 8;

    auto loadB = [&](auto sc) {
        constexpr int s = decltype(sc)::value;
        if constexpr (s < NSTEP) {
#pragma unroll
            for (int ni = 0; ni < NT; ++ni)
#pragma unroll
                for (int ks = 0; ks < 4; ++ks)
                    bfr[s & 1][ni][ks] = *(const bf16x8*)(wlane
                        + (size_t)(s * 8 + ks * 2) * COUT_TOT * 8 + ni * 32 * 8);
        }
    };
    auto loadIdxS = [&](auto sc) {
        constexpr int s = decltype(sc)::value;
        if constexpr (GATHER && s < NSTEP) {
#pragma unroll
            for (int i = 0; i < D; ++i)
                myIdx[s % 3][i] = idxT[(s * IPS) * NN + ioff[i]];
        }
    };
    auto issueDMA = [&](auto sc) {
        constexpr int s = decltype(sc)::value;
        if constexpr (s < NSTEP) {
            char* base = Aw + (s % NBUFS) * (WM * 128);
#pragma unroll
            for (int i = 0; i < D; ++i) {
                const __bf16* src;
                if constexpr (GATHER)
                    src = hin + (size_t)myIdx[s % 3][i] * CIN + koff[i];
                else
                    src = hin + (size_t)gmr[i] * K + s * 64 + coff[i];
                __builtin_amdgcn_global_load_lds(
                    (const __attribute__((address_space(1))) void*)src,
                    (__attribute__((address_space(3))) void*)(base + i * 1024),
                    16, 0, 0);
            }
        }
    };

    f32x16 acc[MT][NT];
#pragma unroll
    for (int mi = 0; mi < MT; ++mi)
#pragma unroll
        for (int ni = 0; ni < NT; ++ni) { f32x16 z = {}; acc[mi][ni] = z; }

    loadIdxS(ic<0>{});
    loadIdxS(ic<1>{});
    memfence_sched();
    loadB(ic<0>{});
    memfence_sched();
    issueDMA(ic<0>{});
    memfence_sched();
    loadIdxS(ic<2>{});
    memfence_sched();

    static_for<NSTEP>([&](auto sc) {
        constexpr int s = decltype(sc)::value;
        loadB(ic<s + 1>{});
        memfence_sched();
        issueDMA(ic<s + 1>{});
        memfence_sched();
        loadIdxS(ic<s + 3>{});
        memfence_sched();
        constexpr int NW = I * (s + 2 < NSTEP) + (Bn + D) * (s + 1 < NSTEP)
                         + I * (s + 3 < NSTEP);
        wait_vmcnt<NW>();
        memfence_sched();

        const char* base = Aw + (s % NBUFS) * (WM * 128);
        bf16x8 afr[MT][4];
#pragma unroll
        for (int mi = 0; mi < MT; ++mi)
#pragma unroll
            for (int ks = 0; ks < 4; ++ks) {
                int cb = ks * 2 + kh;
                afr[mi][ks] = *(const bf16x8*)(base + ((mi * 32 + ml) * 8 + (cb ^ (ml & 7))) * 16);
            }
#pragma unroll
        for (int ks = 0; ks < 4; ++ks)
#pragma unroll
            for (int mi = 0; mi < MT; ++mi)
#pragma unroll
                for (int ni = 0; ni < NT; ++ni)
                    acc[mi][ni] = __builtin_amdgcn_mfma_f32_32x32x16_bf16(
                        afr[mi][ks], bfr[s & 1][ni][ks], acc[mi][ni], 0, 0, 0);
    });

    // ---- epilogue
    __syncthreads();
    if constexpr (OUTF8) {
        unsigned char* Cs8 = (unsigned char*)smem;
        constexpr int LDC8 = COUT_B + 16;
#pragma unroll
        for (int ni = 0; ni < NT; ++ni) {
            const int col = wc * WN + ni * 32 + ml;
            const float bv = bias[col0 + col];
#pragma unroll
            for (int mi = 0; mi < MT; ++mi) {
#pragma unroll
                for (int r = 0; r < 16; ++r) {
                    int row = wr * WM + mi * 32 + ((r & 3) + 8 * (r >> 2) + 4 * kh);
                    Cs8[row * LDC8 + col] = to_fp8(elu_f(acc[mi][ni][r] + bv));
                }
            }
        }
        __syncthreads();
        constexpr int C16 = COUT_B / 16;
#pragma unroll
        for (int j2 = tid; j2 < TILE_M * C16; j2 += 256) {
            int row = j2 / C16, c16 = j2 % C16;
            int gm = m0 + row;
            if (gm < NN)
                *(int4*)((unsigned char*)hout + (size_t)gm * COUT_TOT + col0 + c16 * 16)
                    = *(int4*)&Cs8[row * LDC8 + c16 * 16];
        }
    } else {
        __bf16* Cs = (__bf16*)smem;
        constexpr int LDC = COUT_B + 8;
#pragma unroll
        for (int ni = 0; ni < NT; ++ni) {
            const int col = wc * WN + ni * 32 + ml;
            const float bv = bias[col0 + col];
#pragma unroll
            for (int mi = 0; mi < MT; ++mi) {
#pragma unroll
                for (int r = 0; r < 16; ++r) {
                    int row = wr * WM + mi * 32 + ((r & 3) + 8 * (r >> 2) + 4 * kh);
                    Cs[row * LDC + col] = (__bf16)elu_f(acc[mi][ni][r] + bv);
                }
            }
        }
        __syncthreads();
        constexpr int C8 = COUT_B / 8;
#pragma unroll
        for (int j2 = tid; j2 < TILE_M * C8; j2 += 256) {
            int row = j2 / C8, c8 = j2 % C8;
            int gm = m0 + row;
            if (gm < NN)
                *(int4*)&((__bf16*)hout)[(size_t)gm * COUT_TOT + col0 + c8 * 8] = *(int4*)&Cs[row * LDC + c8 * 8];
        }
    }
}

// ------------------------------------------- spiral3 MIXED: fp8 h2 gather + bf16 MFMA
// TILE 64 (RW=2, CW=2), wave 32x64, K=1024, NSTEP=16.
// A staged ROW-MINOR (R18-verified): inst i, lane t -> row i*16+(t&15), chunk t>>4;
// read addr (ml>>4)*1024 + ks*256 + (ml&15)*16 + kh*8 -> ~4-way conflicts.
// Dequant via HW packed cvt (dq8_fast), w3 bf16 exact.
__global__ __launch_bounds__(256, 3) void mfma3_mixed(const unsigned char* __restrict__ h2f8, // [N,64] e4m3
                                                      const int* __restrict__ idxT,
                                                      const __bf16* __restrict__ Wsw,         // bf16 frag-major (K=1024,C=128)
                                                      const float* __restrict__ bias,
                                                      __bf16* __restrict__ h3)
{
    constexpr int NN = 100000;
    constexpr int NSTEP = 16;
    constexpr int D = 2;        // DMA insts per step per wave (32 rows x 64 B)
    constexpr int Bn = 8;       // B vmem loads per step
    constexpr int I = 2;        // idx loads per step
    __shared__ __align__(16) char smem[17408];   // A: 4x2x2KB=16KB; epilogue 64x136 bf16

    const int tid = threadIdx.x;
    const int lane = tid & 63;
    const int w = tid >> 6;
    const int wr = w >> 1;
    const int wc = w & 1;
    const int ml = lane & 31;
    const int kh = lane >> 5;
    const int m0 = blockIdx.x * 64;
    const int rbase = m0 + wr * 32;

    char* const Aw = smem + w * 4096;

    // row-minor DMA geometry: inst i, lane t -> row i*16+(t&15), chunk t>>4
    int ioff[D], koff;
#pragma unroll
    for (int i = 0; i < D; ++i) {
        int gm = rbase + i * 16 + (lane & 15);
        if (gm >= NN) gm = NN - 1;
        ioff[i] = gm;
    }
    koff = (lane >> 4) * 16;

    bf16x8 bfr[2][2][4];
    int myIdx[3][D];

    const __bf16* wlane = Wsw + ((size_t)(wc * 64 + ml) + (size_t)kh * 128) * 8;

    auto loadB = [&](auto sc) {
        constexpr int s = decltype(sc)::value;
        if constexpr (s < NSTEP) {
#pragma unroll
            for (int ni = 0; ni < 2; ++ni)
#pragma unroll
                for (int ks = 0; ks < 4; ++ks)
                    bfr[s & 1][ni][ks] = *(const bf16x8*)(wlane
                        + (size_t)(s * 8 + ks * 2) * 128 * 8 + ni * 32 * 8);
        }
    };
    auto loadIdxS = [&](auto sc) {
        constexpr int s = decltype(sc)::value;
        if constexpr (s < NSTEP) {
#pragma unroll
            for (int i = 0; i < D; ++i)
                myIdx[s % 3][i] = idxT[(size_t)s * NN + ioff[i]];
        }
    };
    auto issueDMA = [&](auto sc) {
        constexpr int s = decltype(sc)::value;
        if constexpr (s < NSTEP) {
            char* base = Aw + (s & 1) * 2048;
#pragma unroll
            for (int i = 0; i < D; ++i) {
                const unsigned char* src = h2f8 + (size_t)myIdx[s % 3][i] * 64 + koff;
                __builtin_amdgcn_global_load_lds(
                    (const __attribute__((address_space(1))) void*)src,
                    (__attribute__((address_space(3))) void*)(base + i * 1024),
                    16, 0, 0);
            }
        }
    };

    f32x16 acc[2];
    { f32x16 z = {}; acc[0] = z; acc[1] = z; }

    loadIdxS(ic<0>{});
    loadIdxS(ic<1>{});
    memfence_sched();
    loadB(ic<0>{});
    memfence_sched();
    issueDMA(ic<0>{});
    memfence_sched();
    loadIdxS(ic<2>{});
    memfence_sched();

    static_for<NSTEP>([&](auto sc) {
        constexpr int s = decltype(sc)::value;
        loadB(ic<s + 1>{});
        memfence_sched();
        issueDMA(ic<s + 1>{});
        memfence_sched();
        loadIdxS(ic<s + 3>{});
        memfence_sched();
        constexpr int NW = I * (s + 2 < NSTEP) + (Bn + D) * (s + 1 < NSTEP)
                         + I * (s + 3 < NSTEP);
        wait_vmcnt<NW>();
        memfence_sched();

        // A reads, row-minor: addr = (ml>>4)*1024 + ks*256 + (ml&15)*16 + kh*8
        const char* base = Aw + (s & 1) * 2048 + (ml >> 4) * 1024 + (ml & 15) * 16 + kh * 8;
        bf16x8 afr[4];
#pragma unroll
        for (int ks = 0; ks < 4; ++ks) {
            long a8 = *(const long*)(base + ks * 256);
            afr[ks] = dq8_fast(a8);   // HW packed fp8->f32, then bf16 (exact)
        }
#pragma unroll
        for (int ks = 0; ks < 4; ++ks)
#pragma unroll
            for (int ni = 0; ni < 2; ++ni)
                acc[ni] = __builtin_amdgcn_mfma_f32_32x32x16_bf16(
                    afr[ks], bfr[s & 1][ni][ks], acc[ni], 0, 0, 0);
    });

    // ---- epilogue: bf16 h3, coalesced
    __syncthreads();
    __bf16* Cs = (__bf16*)smem;
#pragma unroll
    for (int ni = 0; ni < 2; ++ni) {
        const int col = wc * 64 + ni * 32 + ml;
        const float bv = bias[col];
#pragma unroll
        for (int r = 0; r < 16; ++r) {
            int row = wr * 32 + ((r & 3) + 8 * (r >> 2) + 4 * kh);
            Cs[row * 136 + col] = (__bf16)elu_f(acc[ni][r] + bv);
        }
    }
    __syncthreads();
#pragma unroll
    for (int j2 = tid; j2 < 64 * 16; j2 += 256) {
        int row = j2 >> 4, c8 = j2 & 15;
        int gm = m0 + row;
        if (gm < NN)
            *(int4*)&h3[(size_t)gm * 128 + c8 * 8] = *(int4*)&Cs[row * 136 + c8 * 8];
    }
}

// ------------------------------------------- FUSED fc1 + fc2(MFMA) + log_softmax (R15)
__global__ __launch_bounds__(256, 3) void fc12_kernel(const __bf16* __restrict__ h3,   // [N,128]
                                                      const __bf16* __restrict__ Wsw,  // fc1 frag-major (K=128,C=256)
                                                      const float* __restrict__ bias1,
                                                      const __bf16* __restrict__ W2p,  // fc2 frag-major padded (K=256,C=32)
                                                      const float* __restrict__ bias2,
                                                      float* __restrict__ out)
{
    __shared__ __align__(16) char smem[32 * 264 * 2];
    const int tid = threadIdx.x;
    const int lane = tid & 63;
    const int w = tid >> 6;
    const int ml = lane & 31;
    const int kh = lane >> 5;
    const int m0 = blockIdx.x * 32;

    const __bf16* wlane = Wsw + ((size_t)(w * 64 + ml) + (size_t)kh * 256) * 8;
    bf16x8 bfr[2][2][4];
#pragma unroll
    for (int s = 0; s < 2; ++s)
#pragma unroll
        for (int ni = 0; ni < 2; ++ni)
#pragma unroll
            for (int ks = 0; ks < 4; ++ks)
                bfr[s][ni][ks] = *(const bf16x8*)(wlane
                    + (size_t)(s * 8 + ks * 2) * 256 * 8 + ni * 32 * 8);

    bf16x8 b2f[4];
#pragma unroll
    for (int ks = 0; ks < 4; ++ks)
        b2f[ks] = *(const bf16x8*)&W2p[((w * 8 + ks * 2 + kh) * 32 + ml) * 8];

#pragma unroll
    for (int t = 0; t < 2; ++t) {
        int j = w * 2 + t;
        int lr = j * 4 + (lane >> 4);
        int sc = (lane & 15) ^ (lr & 15);
        const __bf16* src = h3 + (size_t)(m0 + lr) * 128 + sc * 8;
        __builtin_amdgcn_global_load_lds(
            (const __attribute__((address_space(1))) void*)src,
            (__attribute__((address_space(3))) void*)(smem + j * 1024),
            16, 0, 0);
    }
    wait_vmcnt<0>();
    __syncthreads();

    f32x16 acc[2];
    { f32x16 z = {}; acc[0] = z; acc[1] = z; }
    const char* Ab = smem;
#pragma unroll
    for (int s = 0; s < 2; ++s) {
        bf16x8 afr[4];
#pragma unroll
        for (int ks = 0; ks < 4; ++ks) {
            int c16 = s * 8 + ks * 2 + kh;
            afr[ks] = *(const bf16x8*)(Ab + ml * 256 + ((c16 ^ (ml & 15)) * 16));
        }
#pragma unroll
        for (int ks = 0; ks < 4; ++ks)
#pragma unroll
            for (int ni = 0; ni < 2; ++ni)
                acc[ni] = __builtin_amdgcn_mfma_f32_32x32x16_bf16(afr[ks], bfr[s][ni][ks], acc[ni], 0, 0, 0);
    }
    __syncthreads();

    __bf16* Cs = (__bf16*)smem;
#pragma unroll
    for (int ni = 0; ni < 2; ++ni) {
        int col = w * 64 + ni * 32 + ml;
        float bv = bias1[col];
#pragma unroll
        for (int r = 0; r < 16; ++r) {
            int row = (r & 3) + 8 * (r >> 2) + 4 * kh;
            Cs[row * 264 + col] = (__bf16)elu_f(acc[ni][r] + bv);
        }
    }
    __syncthreads();

    bf16x8 a2[4];
#pragma unroll
    for (int ks = 0; ks < 4; ++ks)
        a2[ks] = *(const bf16x8*)&Cs[ml * 264 + w * 64 + ks * 16 + kh * 8];
    f32x16 acc2;
    { f32x16 z = {}; acc2 = z; }
#pragma unroll
    for (int ks = 0; ks < 4; ++ks)
        acc2 = __builtin_amdgcn_mfma_f32_32x32x16_bf16(a2[ks], b2f[ks], acc2, 0, 0, 0);
    __syncthreads();

    float* P = (float*)(smem + w * 4096);
#pragma unroll
    for (int r = 0; r < 16; ++r)
        P[((r & 3) + 8 * (r >> 2) + 4 * kh) * 32 + ml] = acc2[r];
    __syncthreads();

    float4 s4 = make_float4(0.f, 0.f, 0.f, 0.f);
#pragma unroll
    for (int pw = 0; pw < 4; ++pw) {
        float4 v = *(float4*)(smem + pw * 4096 + tid * 16);
        s4.x += v.x; s4.y += v.y; s4.z += v.z; s4.w += v.w;
    }
    __syncthreads();
    *(float4*)(smem + tid * 16) = s4;
    __syncthreads();

    if (tid < 32) {
        const float* L = (float*)smem + tid * 32;
        float logits[12], mx = -1e30f;
#pragma unroll
        for (int o = 0; o < 12; ++o) {
            logits[o] = L[o] + bias2[o];
            mx = fmaxf(mx, logits[o]);
        }
        float s = 0.f;
#pragma unroll
        for (int o = 0; o < 12; ++o) s += expf(logits[o] - mx);
        float lse = mx + logf(s);
        int n = m0 + tid;
        float4 o0 = make_float4(logits[0] - lse, logits[1] - lse, logits[2] - lse, logits[3] - lse);
        float4 o1 = make_float4(logits[4] - lse, logits[5] - lse, logits[6] - lse, logits[7] - lse);
        float4 o2 = make_float4(logits[8] - lse, logits[9] - lse, logits[10] - lse, logits[11] - lse);
        *(float4*)&out[(size_t)n * 12 + 0] = o0;
        *(float4*)&out[(size_t)n * 12 + 4] = o1;
        *(float4*)&out[(size_t)n * 12 + 8] = o2;
    }
}

extern "C" void kernel_launch(void* const* d_in, const int* in_sizes, int n_in,
                              void* d_out, int out_size, void* d_ws, size_t ws_size,
                              hipStream_t stream)
{
    const int N = 100000;
    const float* x     = (const float*)d_in[0];
    const int*   idx   = (const int*)  d_in[1];
    const float* fc0_w = (const float*)d_in[2];
    const float* fc0_b = (const float*)d_in[3];
    const float* w1    = (const float*)d_in[4];
    const float* b1    = (const float*)d_in[5];
    const float* w2    = (const float*)d_in[6];
    const float* b2    = (const float*)d_in[7];
    const float* w3    = (const float*)d_in[8];
    const float* b3    = (const float*)d_in[9];
    const float* fc1_w = (const float*)d_in[10];
    const float* fc1_b = (const float*)d_in[11];
    const float* fc2_w = (const float*)d_in[12];
    const float* fc2_b = (const float*)d_in[13];
    float* out = (float*)d_out;

    // ---- workspace layout
    char* ws = (char*)d_ws;
    const int n_w1 = 32 * 256, n_w2 = 64 * 512, n_w3 = 128 * 1024, n_fc1 = 256 * 128;
    const int n_fc2p = 32 * 256;
    const int n_wb = n_w1 + n_w2 + n_w3 + n_fc1 + n_fc2p;   // 212992
    __bf16* w1b = (__bf16*)ws;
    __bf16* w2b = w1b + n_w1;
    __bf16* w3b = w2b + n_w2;
    __bf16* f1b = w3b + n_w3;
    __bf16* f2b = f1b + n_fc1;
    size_t off = ((size_t)n_wb * 2 + 4095) & ~(size_t)4095;
    int* idxT = (int*)(ws + off);              off += (size_t)N * 16 * 4;
    __bf16* h0 = (__bf16*)(ws + off);          off += (size_t)N * 16 * 2;
    __bf16* h1 = (__bf16*)(ws + off);          off += (size_t)N * 32 * 2;
    unsigned char* h2f8 = (unsigned char*)(ws + off);  off += (size_t)N * 64;
    __bf16* h3 = (__bf16*)(ws + off);          off += (size_t)N * 128 * 2;

    cvt_swz_kernel<<<(n_wb + 255) / 256, 256, 0, stream>>>(w1, w2, w3, fc1_w, fc2_w,
                                                           w1b, w2b, w3b, f1b, f2b);
    idxT_kernel<<<(N * 16 + 255) / 256, 256, 0, stream>>>(idx, idxT, N);
    fc0_kernel<<<(N + 255) / 256, 256, 0, stream>>>(x, fc0_w, fc0_b, h0, N);

    // spiral1: 16ch x16 -> 32 bf16. TILE 128 (RW=4, CW=1), NSTEP=4.
    mfma_layer<16, 16, 32, 32, 128, 4, 1, true, false, 3, 100000>
        <<<dim3((N + 127) / 128, 1), 256, 0, stream>>>(h0, idxT, w1b, b1, (void*)h1);
    // spiral2: 32ch x16 -> 64, OUTPUT fp8 h2. TILE 128 (RW=4, CW=1), NSTEP=8.
    mfma_layer<32, 16, 64, 64, 128, 4, 1, true, true, 3, 100000>
        <<<dim3((N + 127) / 128, 1), 256, 0, stream>>>(h1, idxT, w2b, b2, (void*)h2f8);
    // spiral3 MIXED: fp8 gather (row-minor staging) + HW dequant + bf16 MFMA. [R19]
    mfma3_mixed<<<(N + 63) / 64, 256, 0, stream>>>(h2f8, idxT, w3b, b3, h3);
    // FUSED fc1 + fc2(MFMA) + log_softmax.
    fc12_kernel<<<N / 32, 256, 0, stream>>>(h3, f1b, fc1_b, f2b, fc2_b, out);
}

// Round 20
// 227.795 us; speedup vs baseline: 1.0411x; 1.0047x over previous
//
#include <hip/hip_runtime.h>
#include <hip/hip_fp8.h>
#include <math.h>
#include <utility>

// N = 100000 nodes, SEQ = 16, layers: 3 ->16 ->32 ->64 ->128 ->256 ->12(log_softmax)
// R20 = best-measured configuration (R17, 224.9us):
//   spiral3: fp8 h2 gather (64-B rows, halved line count) + SW dequant + bf16 MFMA,
//   col-XOR staging. R19 proved VALU/LDS-conflict "fixes" don't move wall time —
//   the layer is pinned on the random-gather L2-miss/fabric path (~47 G lines/s,
//   invariant across 9 structural variants R8-R19).
// spiral1/2: R12-proven bf16 depth-1 pipeline (spiral2 epilogue emits fp8 h2).
// fc1+fc2+log_softmax fused with MFMA fc2 (R15-proven).

typedef __bf16 bf16x8 __attribute__((ext_vector_type(8)));
typedef float f32x16 __attribute__((ext_vector_type(16)));

template <int V> using ic = std::integral_constant<int, V>;

template <typename F, int... Is>
__device__ __forceinline__ void static_for_impl(F&& f, std::integer_sequence<int, Is...>) {
    (f(ic<Is>{}), ...);
}
template <int N_, typename F>
__device__ __forceinline__ void static_for(F&& f) {
    static_for_impl(static_cast<F&&>(f), std::make_integer_sequence<int, N_>{});
}

template <int N_>
__device__ __forceinline__ void wait_vmcnt() {
    static_assert(N_ <= 63, "vmcnt range");
    __builtin_amdgcn_s_waitcnt((N_ & 0xF) | (0x7 << 4) | (0xF << 8) | ((N_ >> 4) << 14));
}

__device__ __forceinline__ void memfence_sched() { __builtin_amdgcn_sched_barrier(0x000F); }

__device__ __forceinline__ float elu_f(float v) { return v > 0.f ? v : expm1f(v); }

__device__ __forceinline__ unsigned char to_fp8(float v) {
    __hip_fp8_e4m3 q(v);
    return (unsigned char)q.__x;
}

// 8 packed fp8 e4m3 -> bf16x8 (exact: bf16 is a superset of e4m3)
__device__ __forceinline__ bf16x8 dq8(long v) {
    bf16x8 r;
#pragma unroll
    for (int j = 0; j < 8; ++j) {
        __hip_fp8_e4m3 q;
        q.__x = (unsigned char)(v >> (8 * j));
        r[j] = (__bf16)(float)q;
    }
    return r;
}

// ------------------------------------------------ weight prep (all bf16 frag-major)
// dst chunk ((k/64)*8 + (k%64)/8)*C + col, elem k%8  <- src[col*K+k]
template <int K, int C>
__device__ __forceinline__ void swz_one(const float* __restrict__ src, __bf16* __restrict__ dst, int j)
{
    int col = j / K;
    int k = j & (K - 1);
    int chunk = ((k >> 6) * 8 + ((k & 63) >> 3)) * C + col;
    dst[chunk * 8 + (k & 7)] = (__bf16)src[j];
}

__global__ __launch_bounds__(256) void cvt_swz_kernel(const float* __restrict__ w1,
                                                      const float* __restrict__ w2,
                                                      const float* __restrict__ w3,
                                                      const float* __restrict__ f1,
                                                      const float* __restrict__ f2,
                                                      __bf16* __restrict__ d1,
                                                      __bf16* __restrict__ d2,
                                                      __bf16* __restrict__ d3,
                                                      __bf16* __restrict__ df1,
                                                      __bf16* __restrict__ df2p)
{
    int i = blockIdx.x * 256 + threadIdx.x;
    if (i < 8192)        swz_one<256, 32>(w1, d1, i);
    else if (i < 40960)  swz_one<512, 64>(w2, d2, i - 8192);
    else if (i < 172032) swz_one<1024, 128>(w3, d3, i - 40960);
    else if (i < 204800) swz_one<128, 256>(f1, df1, i - 172032);
    else if (i < 212992) {
        // fc2 padded to 32 cols, frag-major (K=256, C=32); inverse map over DEST index
        int d = i - 204800;
        int e = d & 7;
        int chunkIdx = d >> 3;
        int col = chunkIdx & 31;
        int q = chunkIdx >> 5;
        int k = (q >> 3) * 64 + (q & 7) * 8 + e;
        df2p[d] = (col < 12) ? (__bf16)f2[col * 256 + k] : (__bf16)0.f;
    }
}

// ------------------------------------------------ idx transpose: idxT[s*N + n] = idx[n*16 + s]
__global__ __launch_bounds__(256) void idxT_kernel(const int* __restrict__ idx,
                                                   int* __restrict__ idxT, int N)
{
    int i = blockIdx.x * 256 + threadIdx.x;
    if (i >= N * 16) return;
    int n = i >> 4, s = i & 15;
    idxT[s * N + n] = idx[i];
}

// ---------------------------------------------------------------- fc0: [N,3] -> [N,16] bf16
__global__ __launch_bounds__(256) void fc0_kernel(const float* __restrict__ x,
                                                  const float* __restrict__ w,
                                                  const float* __restrict__ b,
                                                  __bf16* __restrict__ h0, int N)
{
    int n = blockIdx.x * 256 + threadIdx.x;
    if (n >= N) return;
    float x0 = x[n * 3 + 0], x1 = x[n * 3 + 1], x2 = x[n * 3 + 2];
    __bf16 ob[16];
#pragma unroll
    for (int j = 0; j < 16; ++j)
        ob[j] = (__bf16)elu_f(w[j * 3 + 0] * x0 + w[j * 3 + 1] * x1 + w[j * 3 + 2] * x2 + b[j]);
    int4* dst = (int4*)&h0[(size_t)n * 16];
    dst[0] = *(int4*)&ob[0];
    dst[1] = *(int4*)&ob[8];
}

// ------------------------------------------- depth-1 pipelined bf16 MFMA gather-GEMM (R12)
// OUTF8: epilogue emits fp8 e4m3 instead of bf16 (used by spiral2 -> h2).
template <int CIN, int S, int COUT_B, int COUT_TOT, int TILE_M, int RW, int CW,
          bool GATHER, bool OUTF8, int MINW, int NN>
__global__ __launch_bounds__(256, MINW) void mfma_layer(const __bf16* __restrict__ hin,
                                                        const int* __restrict__ idxT,
                                                        const __bf16* __restrict__ Wsw,
                                                        const float* __restrict__ bias,
                                                        void* __restrict__ hout)
{
    constexpr int K = CIN * S;
    constexpr int NSTEP = K / 64;
    static_assert(K % 64 == 0, "K%64");
    constexpr int WM = TILE_M / RW;
    constexpr int WN = COUT_B / CW;
    constexpr int MT = WM / 32;
    constexpr int NT = WN / 32;
    constexpr int IPS = GATHER ? (64 / CIN) : 1;
    constexpr int D = WM / 8;
    constexpr int Bn = NT * 4;
    constexpr int I = GATHER ? D : 0;
    constexpr int NBUFS = 2;
    static_assert(RW * CW == 4, "4 waves");
    static_assert(WM == 32 || WM == 64, "1-2 row subtiles per wave");

    constexpr int AB = 4 * NBUFS * WM * 128;
    constexpr int CB = OUTF8 ? TILE_M * (COUT_B + 16) : TILE_M * (COUT_B + 8) * 2;
    constexpr int SH = AB > CB ? AB : CB;
    __shared__ __align__(16) char smem[SH];

    const int tid = threadIdx.x;
    const int lane = tid & 63;
    const int w = tid >> 6;
    const int wr = w / CW;
    const int wc = w % CW;
    const int ml = lane & 31;
    const int kh = lane >> 5;
    const int m0 = blockIdx.x * TILE_M;
    const int col0 = blockIdx.y * COUT_B;
    const int rbase = m0 + wr * WM;

    char* const Aw = smem + w * (NBUFS * WM * 128);

    int ioff[GATHER ? D : 1];
    int koff[GATHER ? D : 1];
    int gmr[GATHER ? 1 : D];
    int coff[GATHER ? 1 : D];
#pragma unroll
    for (int i = 0; i < D; ++i) {
        int r = i * 8 + (lane >> 3);
        int c = (lane & 7) ^ (r & 7);
        int gm = rbase + r; if (gm >= NN) gm = NN - 1;
        if constexpr (GATHER) {
            ioff[i] = ((c * 8) / CIN) * NN + gm;
            koff[i] = (c * 8) & (CIN - 1);
        } else {
            gmr[i] = gm;
            coff[i] = c * 8;
        }
    }

    bf16x8 bfr[2][NT][4];
    int myIdx[GATHER ? 3 : 1][GATHER ? D : 1];

    const __bf16* wlane = Wsw + ((size_t)(col0 + wc * WN + ml) + (size_t)kh * COUT_TOT) * 8;

    auto loadB = [&](auto sc) {
        constexpr int s = decltype(sc)::value;
        if constexpr (s < NSTEP) {
#pragma unroll
            for (int ni = 0; ni < NT; ++ni)
#pragma unroll
                for (int ks = 0; ks < 4; ++ks)
                    bfr[s & 1][ni][ks] = *(const bf16x8*)(wlane
                        + (size_t)(s * 8 + ks * 2) * COUT_TOT * 8 + ni * 32 * 8);
        }
    };
    auto loadIdxS = [&](auto sc) {
        constexpr int s = decltype(sc)::value;
        if constexpr (GATHER && s < NSTEP) {
#pragma unroll
            for (int i = 0; i < D; ++i)
                myIdx[s % 3][i] = idxT[(s * IPS) * NN + ioff[i]];
        }
    };
    auto issueDMA = [&](auto sc) {
        constexpr int s = decltype(sc)::value;
        if constexpr (s < NSTEP) {
            char* base = Aw + (s % NBUFS) * (WM * 128);
#pragma unroll
            for (int i = 0; i < D; ++i) {
                const __bf16* src;
                if constexpr (GATHER)
                    src = hin + (size_t)myIdx[s % 3][i] * CIN + koff[i];
                else
                    src = hin + (size_t)gmr[i] * K + s * 64 + coff[i];
                __builtin_amdgcn_global_load_lds(
                    (const __attribute__((address_space(1))) void*)src,
                    (__attribute__((address_space(3))) void*)(base + i * 1024),
                    16, 0, 0);
            }
        }
    };

    f32x16 acc[MT][NT];
#pragma unroll
    for (int mi = 0; mi < MT; ++mi)
#pragma unroll
        for (int ni = 0; ni < NT; ++ni) { f32x16 z = {}; acc[mi][ni] = z; }

    loadIdxS(ic<0>{});
    loadIdxS(ic<1>{});
    memfence_sched();
    loadB(ic<0>{});
    memfence_sched();
    issueDMA(ic<0>{});
    memfence_sched();
    loadIdxS(ic<2>{});
    memfence_sched();

    static_for<NSTEP>([&](auto sc) {
        constexpr int s = decltype(sc)::value;
        loadB(ic<s + 1>{});
        memfence_sched();
        issueDMA(ic<s + 1>{});
        memfence_sched();
        loadIdxS(ic<s + 3>{});
        memfence_sched();
        constexpr int NW = I * (s + 2 < NSTEP) + (Bn + D) * (s + 1 < NSTEP)
                         + I * (s + 3 < NSTEP);
        wait_vmcnt<NW>();
        memfence_sched();

        const char* base = Aw + (s % NBUFS) * (WM * 128);
        bf16x8 afr[MT][4];
#pragma unroll
        for (int mi = 0; mi < MT; ++mi)
#pragma unroll
            for (int ks = 0; ks < 4; ++ks) {
                int cb = ks * 2 + kh;
                afr[mi][ks] = *(const bf16x8*)(base + ((mi * 32 + ml) * 8 + (cb ^ (ml & 7))) * 16);
            }
#pragma unroll
        for (int ks = 0; ks < 4; ++ks)
#pragma unroll
            for (int mi = 0; mi < MT; ++mi)
#pragma unroll
                for (int ni = 0; ni < NT; ++ni)
                    acc[mi][ni] = __builtin_amdgcn_mfma_f32_32x32x16_bf16(
                        afr[mi][ks], bfr[s & 1][ni][ks], acc[mi][ni], 0, 0, 0);
    });

    // ---- epilogue
    __syncthreads();
    if constexpr (OUTF8) {
        unsigned char* Cs8 = (unsigned char*)smem;
        constexpr int LDC8 = COUT_B + 16;
#pragma unroll
        for (int ni = 0; ni < NT; ++ni) {
            const int col = wc * WN + ni * 32 + ml;
            const float bv = bias[col0 + col];
#pragma unroll
            for (int mi = 0; mi < MT; ++mi) {
#pragma unroll
                for (int r = 0; r < 16; ++r) {
                    int row = wr * WM + mi * 32 + ((r & 3) + 8 * (r >> 2) + 4 * kh);
                    Cs8[row * LDC8 + col] = to_fp8(elu_f(acc[mi][ni][r] + bv));
                }
            }
        }
        __syncthreads();
        constexpr int C16 = COUT_B / 16;
#pragma unroll
        for (int j2 = tid; j2 < TILE_M * C16; j2 += 256) {
            int row = j2 / C16, c16 = j2 % C16;
            int gm = m0 + row;
            if (gm < NN)
                *(int4*)((unsigned char*)hout + (size_t)gm * COUT_TOT + col0 + c16 * 16)
                    = *(int4*)&Cs8[row * LDC8 + c16 * 16];
        }
    } else {
        __bf16* Cs = (__bf16*)smem;
        constexpr int LDC = COUT_B + 8;
#pragma unroll
        for (int ni = 0; ni < NT; ++ni) {
            const int col = wc * WN + ni * 32 + ml;
            const float bv = bias[col0 + col];
#pragma unroll
            for (int mi = 0; mi < MT; ++mi) {
#pragma unroll
                for (int r = 0; r < 16; ++r) {
                    int row = wr * WM + mi * 32 + ((r & 3) + 8 * (r >> 2) + 4 * kh);
                    Cs[row * LDC + col] = (__bf16)elu_f(acc[mi][ni][r] + bv);
                }
            }
        }
        __syncthreads();
        constexpr int C8 = COUT_B / 8;
#pragma unroll
        for (int j2 = tid; j2 < TILE_M * C8; j2 += 256) {
            int row = j2 / C8, c8 = j2 % C8;
            int gm = m0 + row;
            if (gm < NN)
                *(int4*)&((__bf16*)hout)[(size_t)gm * COUT_TOT + col0 + c8 * 8] = *(int4*)&Cs[row * LDC + c8 * 8];
        }
    }
}

// ------------------------------------------- spiral3 MIXED (R17-exact): fp8 h2 gather + bf16 MFMA
// TILE 64 (RW=2, CW=2), wave 32x64, K=1024, NSTEP=16. A: ds_read_b64 fp8 -> dequant
// to bf16x8 in VGPRs (overlaps gather waits). B: bf16 frag-major w3 (exact).
__global__ __launch_bounds__(256, 3) void mfma3_mixed(const unsigned char* __restrict__ h2f8, // [N,64] e4m3
                                                      const int* __restrict__ idxT,
                                                      const __bf16* __restrict__ Wsw,         // bf16 frag-major (K=1024,C=128)
                                                      const float* __restrict__ bias,
                                                      __bf16* __restrict__ h3)
{
    constexpr int NN = 100000;
    constexpr int NSTEP = 16;
    constexpr int D = 2;        // DMA insts per step per wave (32 rows x 64 B)
    constexpr int Bn = 8;       // B vmem loads per step
    constexpr int I = 2;        // idx loads per step
    __shared__ __align__(16) char smem[17408];   // A: 4x2x2KB=16KB; epilogue 64x136 bf16

    const int tid = threadIdx.x;
    const int lane = tid & 63;
    const int w = tid >> 6;
    const int wr = w >> 1;
    const int wc = w & 1;
    const int ml = lane & 31;
    const int kh = lane >> 5;
    const int m0 = blockIdx.x * 64;
    const int rbase = m0 + wr * 32;

    char* const Aw = smem + w * 4096;

    // DMA geometry: inst i, lane t -> row i*16+(t>>2), phys chunk t&3 holds src chunk (t&3)^(r&3)
    int ioff[D], koff[D];
#pragma unroll
    for (int i = 0; i < D; ++i) {
        int r = i * 16 + (lane >> 2);
        int c = (lane & 3) ^ (r & 3);
        int gm = rbase + r; if (gm >= NN) gm = NN - 1;
        ioff[i] = gm;
        koff[i] = c * 16;
    }

    bf16x8 bfr[2][2][4];
    int myIdx[3][D];

    const __bf16* wlane = Wsw + ((size_t)(wc * 64 + ml) + (size_t)kh * 128) * 8;

    auto loadB = [&](auto sc) {
        constexpr int s = decltype(sc)::value;
        if constexpr (s < NSTEP) {
#pragma unroll
            for (int ni = 0; ni < 2; ++ni)
#pragma unroll
                for (int ks = 0; ks < 4; ++ks)
                    bfr[s & 1][ni][ks] = *(const bf16x8*)(wlane
                        + (size_t)(s * 8 + ks * 2) * 128 * 8 + ni * 32 * 8);
        }
    };
    auto loadIdxS = [&](auto sc) {
        constexpr int s = decltype(sc)::value;
        if constexpr (s < NSTEP) {
#pragma unroll
            for (int i = 0; i < D; ++i)
                myIdx[s % 3][i] = idxT[(size_t)s * NN + ioff[i]];
        }
    };
    auto issueDMA = [&](auto sc) {
        constexpr int s = decltype(sc)::value;
        if constexpr (s < NSTEP) {
            char* base = Aw + (s & 1) * 2048;
#pragma unroll
            for (int i = 0; i < D; ++i) {
                const unsigned char* src = h2f8 + (size_t)myIdx[s % 3][i] * 64 + koff[i];
                __builtin_amdgcn_global_load_lds(
                    (const __attribute__((address_space(1))) void*)src,
                    (__attribute__((address_space(3))) void*)(base + i * 1024),
                    16, 0, 0);
            }
        }
    };

    f32x16 acc[2];
    { f32x16 z = {}; acc[0] = z; acc[1] = z; }

    loadIdxS(ic<0>{});
    loadIdxS(ic<1>{});
    memfence_sched();
    loadB(ic<0>{});
    memfence_sched();
    issueDMA(ic<0>{});
    memfence_sched();
    loadIdxS(ic<2>{});
    memfence_sched();

    static_for<NSTEP>([&](auto sc) {
        constexpr int s = decltype(sc)::value;
        loadB(ic<s + 1>{});
        memfence_sched();
        issueDMA(ic<s + 1>{});
        memfence_sched();
        loadIdxS(ic<s + 3>{});
        memfence_sched();
        constexpr int NW = I * (s + 2 < NSTEP) + (Bn + D) * (s + 1 < NSTEP)
                         + I * (s + 3 < NSTEP);
        wait_vmcnt<NW>();
        memfence_sched();

        const char* base = Aw + (s & 1) * 2048;
        bf16x8 afr[4];
#pragma unroll
        for (int ks = 0; ks < 4; ++ks) {
            long a8 = *(const long*)(base + ml * 64 + ((ks ^ (ml & 3)) << 4) + kh * 8);
            afr[ks] = dq8(a8);   // fp8 e4m3 -> bf16 (exact; overlaps gather waits)
        }
#pragma unroll
        for (int ks = 0; ks < 4; ++ks)
#pragma unroll
            for (int ni = 0; ni < 2; ++ni)
                acc[ni] = __builtin_amdgcn_mfma_f32_32x32x16_bf16(
                    afr[ks], bfr[s & 1][ni][ks], acc[ni], 0, 0, 0);
    });

    // ---- epilogue: bf16 h3, coalesced
    __syncthreads();
    __bf16* Cs = (__bf16*)smem;
#pragma unroll
    for (int ni = 0; ni < 2; ++ni) {
        const int col = wc * 64 + ni * 32 + ml;
        const float bv = bias[col];
#pragma unroll
        for (int r = 0; r < 16; ++r) {
            int row = wr * 32 + ((r & 3) + 8 * (r >> 2) + 4 * kh);
            Cs[row * 136 + col] = (__bf16)elu_f(acc[ni][r] + bv);
        }
    }
    __syncthreads();
#pragma unroll
    for (int j2 = tid; j2 < 64 * 16; j2 += 256) {
        int row = j2 >> 4, c8 = j2 & 15;
        int gm = m0 + row;
        if (gm < NN)
            *(int4*)&h3[(size_t)gm * 128 + c8 * 8] = *(int4*)&Cs[row * 136 + c8 * 8];
    }
}

// ------------------------------------------- FUSED fc1 + fc2(MFMA) + log_softmax (R15)
__global__ __launch_bounds__(256, 3) void fc12_kernel(const __bf16* __restrict__ h3,   // [N,128]
                                                      const __bf16* __restrict__ Wsw,  // fc1 frag-major (K=128,C=256)
                                                      const float* __restrict__ bias1,
                                                      const __bf16* __restrict__ W2p,  // fc2 frag-major padded (K=256,C=32)
                                                      const float* __restrict__ bias2,
                                                      float* __restrict__ out)
{
    __shared__ __align__(16) char smem[32 * 264 * 2];
    const int tid = threadIdx.x;
    const int lane = tid & 63;
    const int w = tid >> 6;
    const int ml = lane & 31;
    const int kh = lane >> 5;
    const int m0 = blockIdx.x * 32;

    const __bf16* wlane = Wsw + ((size_t)(w * 64 + ml) + (size_t)kh * 256) * 8;
    bf16x8 bfr[2][2][4];
#pragma unroll
    for (int s = 0; s < 2; ++s)
#pragma unroll
        for (int ni = 0; ni < 2; ++ni)
#pragma unroll
            for (int ks = 0; ks < 4; ++ks)
                bfr[s][ni][ks] = *(const bf16x8*)(wlane
                    + (size_t)(s * 8 + ks * 2) * 256 * 8 + ni * 32 * 8);

    bf16x8 b2f[4];
#pragma unroll
    for (int ks = 0; ks < 4; ++ks)
        b2f[ks] = *(const bf16x8*)&W2p[((w * 8 + ks * 2 + kh) * 32 + ml) * 8];

#pragma unroll
    for (int t = 0; t < 2; ++t) {
        int j = w * 2 + t;
        int lr = j * 4 + (lane >> 4);
        int sc = (lane & 15) ^ (lr & 15);
        const __bf16* src = h3 + (size_t)(m0 + lr) * 128 + sc * 8;
        __builtin_amdgcn_global_load_lds(
            (const __attribute__((address_space(1))) void*)src,
            (__attribute__((address_space(3))) void*)(smem + j * 1024),
            16, 0, 0);
    }
    wait_vmcnt<0>();
    __syncthreads();

    f32x16 acc[2];
    { f32x16 z = {}; acc[0] = z; acc[1] = z; }
    const char* Ab = smem;
#pragma unroll
    for (int s = 0; s < 2; ++s) {
        bf16x8 afr[4];
#pragma unroll
        for (int ks = 0; ks < 4; ++ks) {
            int c16 = s * 8 + ks * 2 + kh;
            afr[ks] = *(const bf16x8*)(Ab + ml * 256 + ((c16 ^ (ml & 15)) * 16));
        }
#pragma unroll
        for (int ks = 0; ks < 4; ++ks)
#pragma unroll
            for (int ni = 0; ni < 2; ++ni)
                acc[ni] = __builtin_amdgcn_mfma_f32_32x32x16_bf16(afr[ks], bfr[s][ni][ks], acc[ni], 0, 0, 0);
    }
    __syncthreads();

    __bf16* Cs = (__bf16*)smem;
#pragma unroll
    for (int ni = 0; ni < 2; ++ni) {
        int col = w * 64 + ni * 32 + ml;
        float bv = bias1[col];
#pragma unroll
        for (int r = 0; r < 16; ++r) {
            int row = (r & 3) + 8 * (r >> 2) + 4 * kh;
            Cs[row * 264 + col] = (__bf16)elu_f(acc[ni][r] + bv);
        }
    }
    __syncthreads();

    bf16x8 a2[4];
#pragma unroll
    for (int ks = 0; ks < 4; ++ks)
        a2[ks] = *(const bf16x8*)&Cs[ml * 264 + w * 64 + ks * 16 + kh * 8];
    f32x16 acc2;
    { f32x16 z = {}; acc2 = z; }
#pragma unroll
    for (int ks = 0; ks < 4; ++ks)
        acc2 = __builtin_amdgcn_mfma_f32_32x32x16_bf16(a2[ks], b2f[ks], acc2, 0, 0, 0);
    __syncthreads();

    float* P = (float*)(smem + w * 4096);
#pragma unroll
    for (int r = 0; r < 16; ++r)
        P[((r & 3) + 8 * (r >> 2) + 4 * kh) * 32 + ml] = acc2[r];
    __syncthreads();

    float4 s4 = make_float4(0.f, 0.f, 0.f, 0.f);
#pragma unroll
    for (int pw = 0; pw < 4; ++pw) {
        float4 v = *(float4*)(smem + pw * 4096 + tid * 16);
        s4.x += v.x; s4.y += v.y; s4.z += v.z; s4.w += v.w;
    }
    __syncthreads();
    *(float4*)(smem + tid * 16) = s4;
    __syncthreads();

    if (tid < 32) {
        const float* L = (float*)smem + tid * 32;
        float logits[12], mx = -1e30f;
#pragma unroll
        for (int o = 0; o < 12; ++o) {
            logits[o] = L[o] + bias2[o];
            mx = fmaxf(mx, logits[o]);
        }
        float s = 0.f;
#pragma unroll
        for (int o = 0; o < 12; ++o) s += expf(logits[o] - mx);
        float lse = mx + logf(s);
        int n = m0 + tid;
        float4 o0 = make_float4(logits[0] - lse, logits[1] - lse, logits[2] - lse, logits[3] - lse);
        float4 o1 = make_float4(logits[4] - lse, logits[5] - lse, logits[6] - lse, logits[7] - lse);
        float4 o2 = make_float4(logits[8] - lse, logits[9] - lse, logits[10] - lse, logits[11] - lse);
        *(float4*)&out[(size_t)n * 12 + 0] = o0;
        *(float4*)&out[(size_t)n * 12 + 4] = o1;
        *(float4*)&out[(size_t)n * 12 + 8] = o2;
    }
}

extern "C" void kernel_launch(void* const* d_in, const int* in_sizes, int n_in,
                              void* d_out, int out_size, void* d_ws, size_t ws_size,
                              hipStream_t stream)
{
    const int N = 100000;
    const float* x     = (const float*)d_in[0];
    const int*   idx   = (const int*)  d_in[1];
    const float* fc0_w = (const float*)d_in[2];
    const float* fc0_b = (const float*)d_in[3];
    const float* w1    = (const float*)d_in[4];
    const float* b1    = (const float*)d_in[5];
    const float* w2    = (const float*)d_in[6];
    const float* b2    = (const float*)d_in[7];
    const float* w3    = (const float*)d_in[8];
    const float* b3    = (const float*)d_in[9];
    const float* fc1_w = (const float*)d_in[10];
    const float* fc1_b = (const float*)d_in[11];
    const float* fc2_w = (const float*)d_in[12];
    const float* fc2_b = (const float*)d_in[13];
    float* out = (float*)d_out;

    // ---- workspace layout
    char* ws = (char*)d_ws;
    const int n_w1 = 32 * 256, n_w2 = 64 * 512, n_w3 = 128 * 1024, n_fc1 = 256 * 128;
    const int n_fc2p = 32 * 256;
    const int n_wb = n_w1 + n_w2 + n_w3 + n_fc1 + n_fc2p;   // 212992
    __bf16* w1b = (__bf16*)ws;
    __bf16* w2b = w1b + n_w1;
    __bf16* w3b = w2b + n_w2;
    __bf16* f1b = w3b + n_w3;
    __bf16* f2b = f1b + n_fc1;
    size_t off = ((size_t)n_wb * 2 + 4095) & ~(size_t)4095;
    int* idxT = (int*)(ws + off);              off += (size_t)N * 16 * 4;
    __bf16* h0 = (__bf16*)(ws + off);          off += (size_t)N * 16 * 2;
    __bf16* h1 = (__bf16*)(ws + off);          off += (size_t)N * 32 * 2;
    unsigned char* h2f8 = (unsigned char*)(ws + off);  off += (size_t)N * 64;
    __bf16* h3 = (__bf16*)(ws + off);          off += (size_t)N * 128 * 2;

    cvt_swz_kernel<<<(n_wb + 255) / 256, 256, 0, stream>>>(w1, w2, w3, fc1_w, fc2_w,
                                                           w1b, w2b, w3b, f1b, f2b);
    idxT_kernel<<<(N * 16 + 255) / 256, 256, 0, stream>>>(idx, idxT, N);
    fc0_kernel<<<(N + 255) / 256, 256, 0, stream>>>(x, fc0_w, fc0_b, h0, N);

    // spiral1: 16ch x16 -> 32 bf16. TILE 128 (RW=4, CW=1), NSTEP=4.
    mfma_layer<16, 16, 32, 32, 128, 4, 1, true, false, 3, 100000>
        <<<dim3((N + 127) / 128, 1), 256, 0, stream>>>(h0, idxT, w1b, b1, (void*)h1);
    // spiral2: 32ch x16 -> 64, OUTPUT fp8 h2. TILE 128 (RW=4, CW=1), NSTEP=8.
    mfma_layer<32, 16, 64, 64, 128, 4, 1, true, true, 3, 100000>
        <<<dim3((N + 127) / 128, 1), 256, 0, stream>>>(h1, idxT, w2b, b2, (void*)h2f8);
    // spiral3 MIXED (R17-exact): fp8 gather + SW dequant + bf16 MFMA.
    mfma3_mixed<<<(N + 63) / 64, 256, 0, stream>>>(h2f8, idxT, w3b, b3, h3);
    // FUSED fc1 + fc2(MFMA) + log_softmax.
    fc12_kernel<<<N / 32, 256, 0, stream>>>(h3, f1b, fc1_b, f2b, fc2_b, out);
}